// Round 7
// baseline (3978.301 us; speedup 1.0000x reference)
//
#include <hip/hip_runtime.h>

namespace {

constexpr int H   = 64;
constexpr int NIN = 21;
constexpr int T   = 3000;
constexpr int NB  = 2;     // batches per block
constexpr int G   = 256;   // 4*H

__device__ __forceinline__ float sigm(float v) {
    return 1.0f / (1.0f + __expf(-v));
}
__device__ __forceinline__ float tanh_fast(float v) {
    float e = __expf(2.0f * v);
    return 1.0f - 2.0f / (e + 1.0f);
}

// One MAC = one VOP2 v_fmac_f32 with DPP row_ror on src0 (the h operand).
// HW: row_ror:J delivers in[(lane & 48) | ((lane - J) & 15)] — matches the
// (lane - j) & 15 weight gather (verified passing in rounds 3-6).
#define FMAC0(A, Hv, Wv) \
    asm("v_fmac_f32 %0, %2, %3" : "=v"(A) : "0"(A), "v"(Hv), "v"(Wv))
#define FMACJ(A, Hv, Wv, J) \
    asm("v_fmac_f32 %0, %2, %3 row_ror:" #J : "=v"(A) : "0"(A), "v"(Hv), "v"(Wv))

// 16-term rotated dot for both batches; 4 accumulator chains (even/odd J x batch)
#define DOT16(W, OFS, H0, H1, A0E, A0O, A1E, A1O) do {            \
    FMAC0(A0E, H0, W[OFS + 0]);      FMAC0(A1E, H1, W[OFS + 0]);  \
    FMACJ(A0O, H0, W[OFS + 1], 1);   FMACJ(A1O, H1, W[OFS + 1], 1);\
    FMACJ(A0E, H0, W[OFS + 2], 2);   FMACJ(A1E, H1, W[OFS + 2], 2);\
    FMACJ(A0O, H0, W[OFS + 3], 3);   FMACJ(A1O, H1, W[OFS + 3], 3);\
    FMACJ(A0E, H0, W[OFS + 4], 4);   FMACJ(A1E, H1, W[OFS + 4], 4);\
    FMACJ(A0O, H0, W[OFS + 5], 5);   FMACJ(A1O, H1, W[OFS + 5], 5);\
    FMACJ(A0E, H0, W[OFS + 6], 6);   FMACJ(A1E, H1, W[OFS + 6], 6);\
    FMACJ(A0O, H0, W[OFS + 7], 7);   FMACJ(A1O, H1, W[OFS + 7], 7);\
    FMACJ(A0E, H0, W[OFS + 8], 8);   FMACJ(A1E, H1, W[OFS + 8], 8);\
    FMACJ(A0O, H0, W[OFS + 9], 9);   FMACJ(A1O, H1, W[OFS + 9], 9);\
    FMACJ(A0E, H0, W[OFS + 10], 10); FMACJ(A1E, H1, W[OFS + 10], 10);\
    FMACJ(A0O, H0, W[OFS + 11], 11); FMACJ(A1O, H1, W[OFS + 11], 11);\
    FMACJ(A0E, H0, W[OFS + 12], 12); FMACJ(A1E, H1, W[OFS + 12], 12);\
    FMACJ(A0O, H0, W[OFS + 13], 13); FMACJ(A1O, H1, W[OFS + 13], 13);\
    FMACJ(A0E, H0, W[OFS + 14], 14); FMACJ(A1E, H1, W[OFS + 14], 14);\
    FMACJ(A0O, H0, W[OFS + 15], 15); FMACJ(A1O, H1, W[OFS + 15], 15);\
} while (0)

// 16 waves of 64; 4 roles x 4 waves; each lane holds exactly ONE weight row
// in a SINGLE array wA[64] -> per-path VGPR demand ~105 < 128 budget
// (4 waves/SIMD). Rounds 3-6 kept 2-3 arrays live on every path (the unused
// ones were zero-initialized), blowing the budget and forcing AGPR shuttling.
__launch_bounds__(1024, 1)
__global__ void lstm16(const float* __restrict__ x,
                       const float* __restrict__ Wih0, const float* __restrict__ Whh0,
                       const float* __restrict__ bih0, const float* __restrict__ bhh0,
                       const float* __restrict__ Wih1, const float* __restrict__ Whh1,
                       const float* __restrict__ bih1, const float* __restrict__ bhh1,
                       const float* __restrict__ Wfc,  const float* __restrict__ bfc,
                       float* __restrict__ out)
{
    const int tid  = threadIdx.x;
    const int lane = tid & 63;
    const int wid  = tid >> 6;
    const int role = wid >> 2;         // 0:Whh0  1:Wih0(+pointwise)  2:Wih1  3:Whh1
    const int g    = tid & 255;        // gate row within role
    const int b0   = blockIdx.x * NB;

    __shared__ float xs[4][NB][32];    // x staged 2 steps ahead, padded 21->32
    __shared__ float p0h[NB][G];       // Whh0*h1 + bias0
    __shared__ float p0x[NB][G];       // Wih0*x
    __shared__ float p1x[NB][G];       // Wih1*h1
    __shared__ float p1h[NB][G];       // Whh1*h2 + bias1
    __shared__ float h1s[NB][H];
    __shared__ float h2s[NB][H];

    // ---- per-lane weight gather, permuted for the DPP access pattern ----
    // slot J must hold rowW[16m + ((lane - J) & 15)]  (row_ror semantics)
    float wA[64];
    if (role == 1) {
        #pragma unroll
        for (int m = 0; m < 2; ++m)
            #pragma unroll
            for (int j = 0; j < 16; ++j) {
                int k = 16 * m + ((lane - j) & 15);
                wA[m * 16 + j] = (k < NIN) ? Wih0[g * NIN + k] : 0.0f;
            }
        #pragma unroll
        for (int i = 32; i < 64; ++i) wA[i] = 0.0f;
    } else {
        const float* rowH = (role == 0) ? (Whh0 + g * 64)
                          : (role == 2) ? (Wih1 + g * 64)
                                        : (Whh1 + g * 64);
        #pragma unroll
        for (int m = 0; m < 4; ++m)
            #pragma unroll
            for (int j = 0; j < 16; ++j)
                wA[m * 16 + j] = rowH[16 * m + ((lane - j) & 15)];
    }
    const float bias = (role == 0) ? (bih0[g] + bhh0[g])
                     : (role == 3) ? (bih1[g] + bhh1[g]) : 0.0f;

    // zero h buffers; stage x(0) and x(1) (pads written too)
    if (tid < 128) {
        (&h1s[0][0])[tid] = 0.0f;
        (&h2s[0][0])[tid] = 0.0f;
    }
    if (wid < 4 && lane < 32) {
        const int s = wid >> 1;
        const int b = wid & 1;
        float v = 0.0f;
        if (lane < NIN) v = x[((size_t)(b0 + b) * T + s) * NIN + lane];
        xs[s][b][lane] = v;
    }

    float hq1[NB][4];   // h1 replicated: hq1[b][m] = h1[b][16m + (lane&15)]
    float hq2[NB][4];   // h2 replicated (role 3)
    #pragma unroll
    for (int b = 0; b < NB; ++b)
        #pragma unroll
        for (int m = 0; m < 4; ++m) { hq1[b][m] = 0.0f; hq2[b][m] = 0.0f; }

    float c_st = 0.0f;  // c1 on waves 4,5 ; c2 on waves 6,7
    __syncthreads();

    // Pipeline: iteration t computes layer0(t) and layer1(t-1).
    for (int t = 0; t <= T; ++t) {
        // ---------------- phase 1: matvec FMAs ----------------
        if (role == 0) {
            // stage x(t+2) early (waves 0,1); LDS-write after the FMAs
            float xv = 0.0f;
            const bool st = (wid < 2) && (t + 2 < T) && (lane < 32);
            if (st && lane < NIN)
                xv = x[((size_t)(b0 + wid) * T + (t + 2)) * NIN + lane];
            if (t < T) {
                float a0e = bias, a0o = 0.0f, a1e = bias, a1o = 0.0f;
                DOT16(wA, 0,  hq1[0][0], hq1[1][0], a0e, a0o, a1e, a1o);
                DOT16(wA, 16, hq1[0][1], hq1[1][1], a0e, a0o, a1e, a1o);
                DOT16(wA, 32, hq1[0][2], hq1[1][2], a0e, a0o, a1e, a1o);
                DOT16(wA, 48, hq1[0][3], hq1[1][3], a0e, a0o, a1e, a1o);
                p0h[0][g] = a0e + a0o;
                p0h[1][g] = a1e + a1o;
            }
            if (st) xs[(t + 2) & 3][wid][lane] = xv;
        } else if (role == 1) {
            if (t < T) {
                float xq00 = xs[t & 3][0][lane & 15];
                float xq01 = xs[t & 3][0][16 + (lane & 15)];
                float xq10 = xs[t & 3][1][lane & 15];
                float xq11 = xs[t & 3][1][16 + (lane & 15)];
                float a0e = 0.0f, a0o = 0.0f, a1e = 0.0f, a1o = 0.0f;
                DOT16(wA, 0,  xq00, xq10, a0e, a0o, a1e, a1o);
                DOT16(wA, 16, xq01, xq11, a0e, a0o, a1e, a1o);
                p0x[0][g] = a0e + a0o;
                p0x[1][g] = a1e + a1o;
            }
        } else if (role == 2) {
            if (t > 0) {
                float a0e = 0.0f, a0o = 0.0f, a1e = 0.0f, a1o = 0.0f;
                DOT16(wA, 0,  hq1[0][0], hq1[1][0], a0e, a0o, a1e, a1o);
                DOT16(wA, 16, hq1[0][1], hq1[1][1], a0e, a0o, a1e, a1o);
                DOT16(wA, 32, hq1[0][2], hq1[1][2], a0e, a0o, a1e, a1o);
                DOT16(wA, 48, hq1[0][3], hq1[1][3], a0e, a0o, a1e, a1o);
                p1x[0][g] = a0e + a0o;
                p1x[1][g] = a1e + a1o;
            }
        } else {
            if (t > 0) {
                float a0e = bias, a0o = 0.0f, a1e = bias, a1o = 0.0f;
                DOT16(wA, 0,  hq2[0][0], hq2[1][0], a0e, a0o, a1e, a1o);
                DOT16(wA, 16, hq2[0][1], hq2[1][1], a0e, a0o, a1e, a1o);
                DOT16(wA, 32, hq2[0][2], hq2[1][2], a0e, a0o, a1e, a1o);
                DOT16(wA, 48, hq2[0][3], hq2[1][3], a0e, a0o, a1e, a1o);
                p1h[0][g] = a0e + a0o;
                p1h[1][g] = a1e + a1o;
            }
        }
        __syncthreads();

        // ---------------- phase 2: pointwise (role-1 waves, one per SIMD) ----------------
        if (wid == 4 || wid == 5) {
            if (t < T) {                       // layer0 step t
                const int b = wid - 4;
                const int u = lane;
                float gi = p0h[b][u]       + p0x[b][u];
                float gf = p0h[b][64 + u]  + p0x[b][64 + u];
                float gg = p0h[b][128 + u] + p0x[b][128 + u];
                float go = p0h[b][192 + u] + p0x[b][192 + u];
                float i_ = sigm(gi), f_ = sigm(gf), g_ = tanh_fast(gg), o_ = sigm(go);
                c_st = fmaf(f_, c_st, i_ * g_);
                h1s[b][u] = o_ * tanh_fast(c_st);
            }
        } else if (wid == 6 || wid == 7) {
            if (t > 0) {                       // layer1 step t-1
                const int b = wid - 6;
                const int u = lane;
                float gi = p1x[b][u]       + p1h[b][u];
                float gf = p1x[b][64 + u]  + p1h[b][64 + u];
                float gg = p1x[b][128 + u] + p1h[b][128 + u];
                float go = p1x[b][192 + u] + p1h[b][192 + u];
                float i_ = sigm(gi), f_ = sigm(gf), g_ = tanh_fast(gg), o_ = sigm(go);
                c_st = fmaf(f_, c_st, i_ * g_);
                h2s[b][u] = o_ * tanh_fast(c_st);
            }
        }
        __syncthreads();

        if (t == T) break;

        // ---------------- phase 3: redistribute h into rotation registers ----------------
        if (role == 0 || role == 2) {
            #pragma unroll
            for (int b = 0; b < NB; ++b)
                #pragma unroll
                for (int m = 0; m < 4; ++m)
                    hq1[b][m] = h1s[b][16 * m + (lane & 15)];
        } else if (role == 3) {
            #pragma unroll
            for (int b = 0; b < NB; ++b)
                #pragma unroll
                for (int m = 0; m < 4; ++m)
                    hq2[b][m] = h2s[b][16 * m + (lane & 15)];
        }
    }

    // ---------------- FC epilogue: out[b] = dot(h2, Wfc) + bfc ----------------
    if (tid < 128) {
        const int b = tid >> 6;
        float v = h2s[b][lane] * Wfc[lane];
        #pragma unroll
        for (int off = 32; off > 0; off >>= 1)
            v += __shfl_down(v, off, 64);
        if (lane == 0) out[b0 + b] = v + bfc[0];
    }
}

} // namespace

extern "C" void kernel_launch(void* const* d_in, const int* in_sizes, int n_in,
                              void* d_out, int out_size, void* d_ws, size_t ws_size,
                              hipStream_t stream)
{
    const float* x    = (const float*)d_in[0];
    const float* Wih0 = (const float*)d_in[1];
    const float* Whh0 = (const float*)d_in[2];
    const float* bih0 = (const float*)d_in[3];
    const float* bhh0 = (const float*)d_in[4];
    const float* Wih1 = (const float*)d_in[5];
    const float* Whh1 = (const float*)d_in[6];
    const float* bih1 = (const float*)d_in[7];
    const float* bhh1 = (const float*)d_in[8];
    const float* Wfc  = (const float*)d_in[9];
    const float* bfc  = (const float*)d_in[10];
    float* out = (float*)d_out;

    hipLaunchKernelGGL(lstm16, dim3(512 / NB), dim3(1024), 0, stream,
                       x, Wih0, Whh0, bih0, bhh0, Wih1, Whh1, bih1, bhh1,
                       Wfc, bfc, out);
}